// Round 15
// baseline (470.165 us; speedup 1.0000x reference)
//
#include <hip/hip_runtime.h>
#include <hip/hip_bf16.h>

// Problem constants (fixed by the reference)
#define N_NODES 4096
#define N_EDGES 32768
#define BATCH   1024
#define NFEAT   32
#define EFEAT   16
#define ENCD    64
#define HIDD    128
#define HEADS   4
#define HID4    512
#define MAXS    10
#define TVAR    1536   // 3*HID4: [src-attn | tgt-attn | tgt-msg] node tables

typedef unsigned short ushort_t;
typedef __bf16 bf16x8 __attribute__((ext_vector_type(8)));
typedef float f32x4 __attribute__((ext_vector_type(4)));

static __device__ __forceinline__ float bfbits2f(unsigned int hi16) {
    return __uint_as_float(hi16);
}
static __device__ __forceinline__ void unpack8(uint4 v, float* f) {
    f[0] = bfbits2f(v.x << 16); f[1] = bfbits2f(v.x & 0xffff0000u);
    f[2] = bfbits2f(v.y << 16); f[3] = bfbits2f(v.y & 0xffff0000u);
    f[4] = bfbits2f(v.z << 16); f[5] = bfbits2f(v.z & 0xffff0000u);
    f[6] = bfbits2f(v.w << 16); f[7] = bfbits2f(v.w & 0xffff0000u);
}
static __device__ __forceinline__ void load8bf(const ushort_t* p, float* f) {
    unpack8(*reinterpret_cast<const uint4*>(p), f);
}
static __device__ __forceinline__ unsigned short f2bf(float x) {
    __hip_bfloat16 h = __float2bfloat16(x);
    return *reinterpret_cast<unsigned short*>(&h);
}
static __device__ __forceinline__ unsigned addpack(unsigned s, unsigned a) {
    float s0 = bfbits2f(s << 16), s1 = bfbits2f(s & 0xffff0000u);
    float a0 = bfbits2f(a << 16), a1 = bfbits2f(a & 0xffff0000u);
    unsigned r0 = f2bf(s0 + a0), r1 = f2bf(s1 + a1);
    return r0 | (r1 << 16);
}
static __device__ __forceinline__ uint4 pack8(const float* f) {
    uint4 u;
    u.x = (unsigned)f2bf(f[0]) | ((unsigned)f2bf(f[1]) << 16);
    u.y = (unsigned)f2bf(f[2]) | ((unsigned)f2bf(f[3]) << 16);
    u.z = (unsigned)f2bf(f[4]) | ((unsigned)f2bf(f[5]) << 16);
    u.w = (unsigned)f2bf(f[6]) | ((unsigned)f2bf(f[7]) << 16);
    return u;
}

// Fragment-swizzled layout for a [rows][K] bf16 operand of mfma_f32_16x16x32_bf16:
//   element (row, k) lives at ((panel*NQ + q)*64 + kgrp*16 + r)*8 + j
//   panel=row>>4, r=row&15, q=k>>5, kgrp=(k>>3)&3, j=k&7

// ========== single-block build: sort by n_states desc + CSR (permuted) + tgtp ==========
__global__ __launch_bounds__(1024) void k_build(const int* __restrict__ nst,
                                                const int* __restrict__ src,
                                                const int* __restrict__ tgt,
                                                int* __restrict__ perm, int* __restrict__ inv,
                                                int* __restrict__ offs, int* __restrict__ eids,
                                                int* __restrict__ tgtp, int* __restrict__ cntAct) {
    __shared__ int bcnt[16], bcur[16];
    __shared__ int inv_l[N_NODES];
    __shared__ int work[N_NODES];     // deg -> cursor
    __shared__ int ssum[1024];
    const int t = threadIdx.x;
    if (t < 16) bcnt[t] = 0;
    __syncthreads();
#pragma unroll
    for (int i = 0; i < 4; ++i) {
        int n = t + i * 1024;
        atomicAdd(&bcnt[10 - nst[n]], 1);   // bucket b holds ns = 10 - b
    }
    __syncthreads();
    if (t == 0) {
        int pref[11]; int run = 0;
        for (int b = 0; b < 10; ++b) { pref[b] = run; run += bcnt[b]; }
        pref[10] = run;
        for (int b = 0; b < 10; ++b) bcur[b] = pref[b];
        for (int i = 0; i < 10; ++i) cntAct[i] = pref[10 - i];   // #nodes with ns > i
    }
    __syncthreads();
#pragma unroll
    for (int i = 0; i < 4; ++i) {
        int n = t + i * 1024;
        int pos = atomicAdd(&bcur[10 - nst[n]], 1);
        perm[pos] = n; inv[n] = pos; inv_l[n] = pos;
    }
#pragma unroll
    for (int i = 0; i < 4; ++i) work[t + i * 1024] = 0;
    __syncthreads();
#pragma unroll
    for (int i = 0; i < 32; ++i) {
        int e = t + i * 1024;
        atomicAdd(&work[inv_l[src[e]]], 1);
    }
    __syncthreads();
    int d0 = work[t * 4], d1 = work[t * 4 + 1], d2 = work[t * 4 + 2], d3 = work[t * 4 + 3];
    int s = d0 + d1 + d2 + d3;
    ssum[t] = s; __syncthreads();
    for (int o = 1; o < 1024; o <<= 1) {
        int v = (t >= o) ? ssum[t - o] : 0;
        __syncthreads();
        ssum[t] += v;
        __syncthreads();
    }
    int run = ssum[t] - s;
    offs[t * 4] = run;     work[t * 4] = run;     run += d0;
    offs[t * 4 + 1] = run; work[t * 4 + 1] = run; run += d1;
    offs[t * 4 + 2] = run; work[t * 4 + 2] = run; run += d2;
    offs[t * 4 + 3] = run; work[t * 4 + 3] = run;
    if (t == 1023) offs[4096] = run + d3;
    __syncthreads();
#pragma unroll
    for (int i = 0; i < 32; ++i) {
        int e = t + i * 1024;
        int pos = atomicAdd(&work[inv_l[src[e]]], 1);
        eids[pos] = e;
        tgtp[pos] = inv_l[tgt[e]];
    }
}

// ================= weight composition / packing =================
__global__ __launch_bounds__(256) void k_comp_eam(const float* __restrict__ We,
                                                  const float* __restrict__ Wa,
                                                  const float* __restrict__ Wm,
                                                  ushort_t* __restrict__ out) {
    __shared__ float w_lds[128][17];
    const int t = threadIdx.x;
    const int p = blockIdx.x;          // 64 panels
    const int cl = t & 15, kbase = t >> 4;
    const int c = p * 16 + cl;
#pragma unroll
    for (int i = 0; i < 8; ++i) {
        int kk = kbase + i * 16;
        w_lds[kk][cl] = (c < 512) ? Wa[(256 + kk) * HID4 + c] : Wm[kk * HID4 + (c - 512)];
    }
    __syncthreads();
    const int k = t >> 4;
    float s = 0.f;
    for (int kk = 0; kk < 128; ++kk)
        s = fmaf(We[k * 128 + kk], w_lds[kk][cl], s);
    int l = ((k >> 3) << 4) + cl, j = k & 7;
    out[((size_t)(p * 64 + l)) * 8 + j] = f2bf(s);
    if (t < 32) {
        uint4 z = {0, 0, 0, 0};
        *(uint4*)(out + ((size_t)(p * 64 + 32 + t)) * 8) = z;
    }
}

__global__ __launch_bounds__(256) void k_comp_fix(const float* __restrict__ Wh,
                                                  const float* __restrict__ Wa,
                                                  const float* __restrict__ Wm,
                                                  ushort_t* __restrict__ out) {
    __shared__ float w_lds[128][17];
    const int t = threadIdx.x;
    const int p = blockIdx.x;          // 96 panels
    const int cl = t & 15, kbase = t >> 4;
    const int c = p * 16 + cl;
#pragma unroll
    for (int i = 0; i < 8; ++i) {
        int kk = kbase + i * 16;
        w_lds[kk][cl] = (c < 512) ? Wa[(128 + kk) * HID4 + c]
                      : (c < 1024) ? Wa[(512 + kk) * HID4 + (c - 512)]
                                   : Wm[(256 + kk) * HID4 + (c - 1024)];
    }
    __syncthreads();
    const int k1 = t >> 4, k2 = k1 + 16;
    float s1 = 0.f, s2 = 0.f;
    for (int kk = 0; kk < 128; ++kk) {
        float wv = w_lds[kk][cl];
        s1 = fmaf(Wh[k1 * 128 + kk], wv, s1);
        s2 = fmaf(Wh[k2 * 128 + kk], wv, s2);
    }
    int l1 = ((k1 >> 3) << 4) + cl, j1 = k1 & 7;
    int l2 = ((k2 >> 3) << 4) + cl, j2 = k2 & 7;
    out[((size_t)(p * 64 + l1)) * 8 + j1] = f2bf(s1);
    out[((size_t)(p * 64 + l2)) * 8 + j2] = f2bf(s2);
}

__global__ void k_pack_var(const float* __restrict__ Wa, const float* __restrict__ Wm,
                           ushort_t* __restrict__ out) {
    int idx = blockIdx.x * blockDim.x + threadIdx.x;   // 96 panels * 4 q * 64 lanes
    int p = idx >> 8, rem = idx & 255;
    int q = rem >> 6, l = rem & 63;
    int c = p * 16 + (l & 15);
    int k0 = q * 32 + ((l >> 4) << 3);
    float v[8];
#pragma unroll
    for (int j = 0; j < 8; ++j) {
        int k = k0 + j;
        v[j] = (c < 512) ? Wa[k * HID4 + c]
             : (c < 1024) ? Wa[(384 + k) * HID4 + (c - 512)]
                          : Wm[(128 + k) * HID4 + (c - 1024)];
    }
    *(uint4*)(out + (size_t)idx * 8) = pack8(v);
}

// ---- efp_sw in CSR order + maskp computation (folded k_mask)
__global__ void k_prep_ef(const float* __restrict__ ef, const int* __restrict__ eids,
                          ushort_t* __restrict__ out, int* __restrict__ maskp) {
    int idx = blockIdx.x * blockDim.x + threadIdx.x;   // 2048 panels * 64 lanes
    int p = idx >> 6, l = idx & 63;
    int slot = p * 16 + (l & 15);
    int e = eids[slot];
    int k0 = (l >> 4) << 3;
    float v[8];
    int mk = 0;
#pragma unroll
    for (int j = 0; j < 8; ++j) {
        int k = k0 + j;
        v[j] = (k < 16) ? ef[e * EFEAT + k] : 0.f;
        mk |= (v[j] != 0.f);
    }
    mk |= __shfl_xor(mk, 16);
    mk |= __shfl_xor(mk, 32);
    if ((l >> 4) == 0) maskp[slot] = mk;
    *(uint4*)(out + (size_t)idx * 8) = pack8(v);
}

// ---- nfp_sw in PERMUTED node order
__global__ void k_prep_nf(const float* __restrict__ nf, const int* __restrict__ perm,
                          ushort_t* __restrict__ out) {
    int idx = blockIdx.x * blockDim.x + threadIdx.x;   // 256 panels * 64 lanes
    int p = idx >> 6, l = idx & 63;
    int n = perm[p * 16 + (l & 15)];
    int k0 = (l >> 4) << 3;
    float v[8];
#pragma unroll
    for (int j = 0; j < 8; ++j) v[j] = nf[n * NFEAT + k0 + j];
    *(uint4*)(out + (size_t)idx * 8) = pack8(v);
}

// ---- h0: permuted row = inv[n]; f32 natural + bf16 swizzled
__global__ void k_h0(const float* __restrict__ nf, const float* __restrict__ Wh,
                     const int* __restrict__ inv,
                     float* __restrict__ h, ushort_t* __restrict__ hbf) {
    int idx = blockIdx.x * blockDim.x + threadIdx.x;   // N*HID
    int n = idx >> 7, c = idx & 127;
    float s = 0.f;
#pragma unroll
    for (int k = 0; k < NFEAT; ++k) s += nf[n * NFEAT + k] * Wh[k * HIDD + c];
    int row = inv[n];
    h[(size_t)row * HIDD + c] = s;
    int p = row >> 4, r = row & 15, q = c >> 5, kg = (c >> 3) & 3, j = c & 7;
    hbf[(size_t)(((p * 4 + q) * 64) + kg * 16 + r) * 8 + j] = f2bf(s);
}

// ================= K=32 swizzled GEMM (setup) =================
__global__ __launch_bounds__(256) void k_gemm32(const ushort_t* __restrict__ A_sw,
                                                const ushort_t* __restrict__ B_sw,
                                                ushort_t* __restrict__ C, int NC) {
    __shared__ ushort_t lds[4][64][64];
    const int tid = threadIdx.x;
    const int l = tid & 63;
    const int w = tid >> 6;
    const int mpb = blockIdx.y * 16 + w * 4;
    const int cpb = blockIdx.x * 4;

    bf16x8 a[4], b[4];
#pragma unroll
    for (int mi = 0; mi < 4; ++mi)
        a[mi] = *(const bf16x8*)(A_sw + (size_t)((mpb + mi) * 64 + l) * 8);
#pragma unroll
    for (int ct = 0; ct < 4; ++ct)
        b[ct] = *(const bf16x8*)(B_sw + (size_t)((cpb + ct) * 64 + l) * 8);

    const int rb = (l >> 4) << 2, lc = l & 15;
#pragma unroll
    for (int mi = 0; mi < 4; ++mi)
#pragma unroll
        for (int ct = 0; ct < 4; ++ct) {
            f32x4 c = {0.f, 0.f, 0.f, 0.f};
            c = __builtin_amdgcn_mfma_f32_16x16x32_bf16(a[mi], b[ct], c, 0, 0, 0);
#pragma unroll
            for (int r = 0; r < 4; ++r)
                lds[w][mi * 16 + rb + r][ct * 16 + lc] = f2bf(c[r]);
        }
    __syncthreads();
#pragma unroll
    for (int i = 0; i < 8; ++i) {
        int ch = (i << 6) + l;
        int row = ch >> 3, co = (ch & 7) << 3;
        int grow = blockIdx.y * 256 + w * 64 + row;
        size_t gidx = (size_t)grow * NC + blockIdx.x * 64 + co;
        *(uint4*)(C + gidx) = *(const uint4*)(&lds[w][row][co]);
    }
}

// ================= K=128 swizzled GEMM + Cadd, frozen-prefix block skip =================
__global__ __launch_bounds__(256) void k_gemm128(const ushort_t* __restrict__ A_sw,
                                                 const ushort_t* __restrict__ B_sw,
                                                 const ushort_t* __restrict__ Cadd,
                                                 ushort_t* __restrict__ C, int NC,
                                                 const int* __restrict__ cntAct, int iter) {
    const int thr = (iter == 0) ? N_NODES : cntAct[iter - 1];
    if ((int)(blockIdx.y * 128) >= thr) return;

    __shared__ ushort_t lds[4][32][64];
    const int tid = threadIdx.x;
    const int l = tid & 63;
    const int w = tid >> 6;
    const int mpb = blockIdx.y * 8 + w * 2;
    const int cpb = blockIdx.x * 4;

    bf16x8 a[2][4], b[4][4];
#pragma unroll
    for (int mi = 0; mi < 2; ++mi)
#pragma unroll
        for (int q = 0; q < 4; ++q)
            a[mi][q] = *(const bf16x8*)(A_sw + (size_t)(((mpb + mi) * 4 + q) * 64 + l) * 8);
#pragma unroll
    for (int ct = 0; ct < 4; ++ct)
#pragma unroll
        for (int q = 0; q < 4; ++q)
            b[ct][q] = *(const bf16x8*)(B_sw + (size_t)(((cpb + ct) * 4 + q) * 64 + l) * 8);

    const int rb = (l >> 4) << 2, lc = l & 15;
#pragma unroll
    for (int mi = 0; mi < 2; ++mi)
#pragma unroll
        for (int ct = 0; ct < 4; ++ct) {
            f32x4 c = {0.f, 0.f, 0.f, 0.f};
#pragma unroll
            for (int q = 0; q < 4; ++q)
                c = __builtin_amdgcn_mfma_f32_16x16x32_bf16(a[mi][q], b[ct][q], c, 0, 0, 0);
#pragma unroll
            for (int r = 0; r < 4; ++r)
                lds[w][mi * 16 + rb + r][ct * 16 + lc] = f2bf(c[r]);
        }
    __syncthreads();
#pragma unroll
    for (int i = 0; i < 4; ++i) {
        int ch = (i << 6) + l;
        int row = ch >> 3, co = (ch & 7) << 3;
        int grow = blockIdx.y * 128 + w * 32 + row;
        size_t gidx = (size_t)grow * NC + blockIdx.x * 64 + co;
        uint4 sv = *(const uint4*)(&lds[w][row][co]);
        uint4 av = *(const uint4*)(Cadd + gidx);
        sv.x = addpack(sv.x, av.x);
        sv.y = addpack(sv.y, av.y);
        sv.z = addpack(sv.z, av.z);
        sv.w = addpack(sv.w, av.w);
        *(uint4*)(C + gidx) = sv;
    }
}

// ===== fused edge pass: PAIR-wise (2 edges/step, pair-ahead prefetch), in-place h =====
#define PREF(qa)                                                                  \
    do {                                                                          \
        int _t1 = tgtp[qa]; nmk1 = maskp[qa];                                     \
        nA1  = *(const uint4*)(eam + (size_t)(qa) * 1024 + c0);                   \
        nM1  = *(const uint4*)(eam + (size_t)(qa) * 1024 + 512 + c0);             \
        nT1  = *(const uint4*)(T + (size_t)_t1 * TVAR + 512 + c0);                \
        nTM1 = *(const uint4*)(T + (size_t)_t1 * TVAR + 1024 + c0);               \
        int _qb = (qa) + 1;                                                       \
        if (_qb < e1) {                                                           \
            int _t2 = tgtp[_qb]; nmk2 = maskp[_qb];                               \
            nA2  = *(const uint4*)(eam + (size_t)_qb * 1024 + c0);                \
            nM2  = *(const uint4*)(eam + (size_t)_qb * 1024 + 512 + c0);          \
            nT2  = *(const uint4*)(T + (size_t)_t2 * TVAR + 512 + c0);            \
            nTM2 = *(const uint4*)(T + (size_t)_t2 * TVAR + 1024 + c0);           \
        } else { nmk2 = 0; nA2 = nA1; nM2 = nM1; nT2 = nT1; nTM2 = nTM1; }        \
    } while (0)

__global__ __launch_bounds__(256) void k_edge(const ushort_t* __restrict__ T,
                                              const ushort_t* __restrict__ eam,
                                              const int* __restrict__ tgtp,
                                              const int* __restrict__ offs,
                                              const int* __restrict__ maskp,
                                              const float* __restrict__ a_kern,
                                              const int* __restrict__ cntAct,
                                              float* __restrict__ h,
                                              ushort_t* __restrict__ hbf, int iter) {
    const int n = (blockIdx.x << 2) + (threadIdx.x >> 6);
    if (n >= cntAct[iter]) return;     // frozen prefix-exit (in-place h untouched)

    const int lane = threadIdx.x & 63;
    const int c0 = lane << 3;
    const int e0 = offs[n], e1 = offs[n + 1];

    float ak[8];
    {
        const float4* p = reinterpret_cast<const float4*>(a_kern + ((lane & 15) << 3));
        float4 a0 = p[0], a1 = p[1];
        ak[0] = a0.x; ak[1] = a0.y; ak[2] = a0.z; ak[3] = a0.w;
        ak[4] = a1.x; ak[5] = a1.y; ak[6] = a1.z; ak[7] = a1.w;
    }
    float asrc[8];
    load8bf(T + (size_t)n * TVAR + c0, asrc);

    float m = -INFINITY, s = 0.f;
    float acc[8] = {0, 0, 0, 0, 0, 0, 0, 0};

    uint4 nA1, nM1, nT1, nTM1, nA2, nM2, nT2, nTM2;
    int nmk1 = 0, nmk2 = 0;
    if (e0 < e1) PREF(e0);

    for (int q = e0; q < e1; q += 2) {
        uint4 A1 = nA1, M1 = nM1, T1 = nT1, TM1 = nTM1;
        uint4 A2 = nA2, M2 = nM2, T2 = nT2, TM2 = nTM2;
        int mk1 = nmk1, mk2 = nmk2;
        int qn = q + 2;
        if (qn < e1) PREF(qn);

        float ea1[8], tt1[8], em1[8], tm1[8], ea2[8], tt2[8], em2[8], tm2[8];
        unpack8(A1, ea1); unpack8(T1, tt1); unpack8(M1, em1); unpack8(TM1, tm1);
        unpack8(A2, ea2); unpack8(T2, tt2); unpack8(M2, em2); unpack8(TM2, tm2);
        float p1 = 0.f, p2 = 0.f;
#pragma unroll
        for (int j = 0; j < 8; ++j) {
            float v1 = asrc[j] + ea1[j] + tt1[j];
            float v2 = asrc[j] + ea2[j] + tt2[j];
            v1 = (v1 > 0.f) ? v1 : 0.2f * v1;      // leaky_relu 0.2
            v2 = (v2 > 0.f) ? v2 : 0.2f * v2;
            p1 = fmaf(v1, ak[j], p1);
            p2 = fmaf(v2, ak[j], p2);
        }
        p1 += __shfl_xor(p1, 1); p2 += __shfl_xor(p2, 1);
        p1 += __shfl_xor(p1, 2); p2 += __shfl_xor(p2, 2);
        p1 += __shfl_xor(p1, 4); p2 += __shfl_xor(p2, 4);
        p1 += __shfl_xor(p1, 8); p2 += __shfl_xor(p2, 8);   // per-head logits
        p1 = mk1 ? p1 : -INFINITY;
        p2 = mk2 ? p2 : -INFINITY;
        float mn = fmaxf(m, fmaxf(p1, p2));
        bool live = (mn != -INFINITY);
        float w1 = live ? __expf(p1 - mn) : 0.f;
        float w2 = live ? __expf(p2 - mn) : 0.f;
        float sc = live ? __expf(m - mn) : 0.f;
        s = s * sc + w1 + w2;
#pragma unroll
        for (int j = 0; j < 8; ++j)
            acc[j] = acc[j] * sc + w1 * (em1[j] + tm1[j]) + w2 * (em2[j] + tm2[j]);
        m = mn;
    }
    if (e1 > e0 && m == -INFINITY) {
        // dead node (all edges masked): uniform attention over ALL its edges
        s = (float)(e1 - e0);
        for (int q = e0; q < e1; ++q) {
            int t = tgtp[q];
            float em[8], tm[8];
            load8bf(eam + (size_t)q * 1024 + 512 + c0, em);
            load8bf(T + (size_t)t * TVAR + 1024 + c0, tm);
#pragma unroll
            for (int j = 0; j < 8; ++j) acc[j] += em[j] + tm[j];
        }
    }
    float inv_s = (e1 > e0) ? (1.f / s) : 0.f;
    float r[8];
#pragma unroll
    for (int j = 0; j < 8; ++j) {
        float v = acc[j] * inv_s;
        v += __shfl_xor(v, 16);
        v += __shfl_xor(v, 32);
        r[j] = v;
    }
    if (lane < 16) {
        float out[8];
#pragma unroll
        for (int j = 0; j < 8; ++j) out[j] = tanhf(r[j]);
        float4* ph = reinterpret_cast<float4*>(h + (size_t)n * HIDD + c0);
        float4 o0, o1;
        o0.x = out[0]; o0.y = out[1]; o0.z = out[2]; o0.w = out[3];
        o1.x = out[4]; o1.y = out[5]; o1.z = out[6]; o1.w = out[7];
        ph[0] = o0; ph[1] = o1;
        int p = n >> 4, rr = n & 15, q = lane >> 2, kg = lane & 3;
        *(uint4*)(hbf + (size_t)(((p * 4 + q) * 64) + kg * 16 + rr) * 8) = pack8(out);
    }
}

// ---------------- out = h[inv[cs]] @ W_g ----------------
__global__ void k_out(const float* __restrict__ h, const int* __restrict__ cs,
                      const int* __restrict__ inv, const float* __restrict__ Wg,
                      float* __restrict__ out) {
    int idx = blockIdx.x * blockDim.x + threadIdx.x;   // B*ENC
    int b = idx >> 6, c = idx & 63;
    int n = inv[cs[b]];
    float s = 0.f;
#pragma unroll
    for (int k = 0; k < HIDD; ++k) s += h[(size_t)n * HIDD + k] * Wg[k * ENCD + c];
    out[idx] = s;
}

extern "C" void kernel_launch(void* const* d_in, const int* in_sizes, int n_in,
                              void* d_out, int out_size, void* d_ws, size_t ws_size,
                              hipStream_t stream) {
    const float* nf  = (const float*)d_in[0];
    const float* ef  = (const float*)d_in[1];
    const int* eidx  = (const int*)d_in[2];
    const int* cs    = (const int*)d_in[3];
    const int* nst   = (const int*)d_in[4];
    const float* Wh  = (const float*)d_in[5];
    const float* We  = (const float*)d_in[6];
    const float* Wa  = (const float*)d_in[7];
    const float* Wm  = (const float*)d_in[8];
    const float* akn = (const float*)d_in[9];
    const float* Wg  = (const float*)d_in[10];
    const int* src = eidx;
    const int* tgt = eidx + N_EDGES;

    char* w = (char*)d_ws;
    size_t off = 0;
    auto alloc = [&](size_t bytes) -> void* {
        void* p = w + off;
        off = (off + bytes + 255) & ~(size_t)255;
        return p;
    };
    float* h         = (float*)alloc((size_t)N_NODES * HIDD * 4);      // in-place
    ushort_t* hbf    = (ushort_t*)alloc((size_t)N_NODES * HIDD * 2);   // in-place swizzled
    ushort_t* eam    = (ushort_t*)alloc((size_t)N_EDGES * 1024 * 2);   // 64 MB, CSR order
    ushort_t* Tfix   = (ushort_t*)alloc((size_t)N_NODES * TVAR * 2);   // permuted rows
    ushort_t* Tcur   = (ushort_t*)alloc((size_t)N_NODES * TVAR * 2);
    ushort_t* Wcomb  = (ushort_t*)alloc((size_t)64 * 64 * 8 * 2);
    ushort_t* WfixC  = (ushort_t*)alloc((size_t)96 * 64 * 8 * 2);
    ushort_t* WvarSw = (ushort_t*)alloc((size_t)96 * 4 * 64 * 8 * 2);
    ushort_t* efp    = (ushort_t*)alloc((size_t)2048 * 64 * 8 * 2);
    ushort_t* nfp    = (ushort_t*)alloc((size_t)256 * 64 * 8 * 2);
    int* offs        = (int*)alloc((size_t)(N_NODES + 1) * 4);
    int* perm        = (int*)alloc((size_t)N_NODES * 4);
    int* inv         = (int*)alloc((size_t)N_NODES * 4);
    int* eids        = (int*)alloc((size_t)N_EDGES * 4);
    int* tgtp        = (int*)alloc((size_t)N_EDGES * 4);
    int* maskp       = (int*)alloc((size_t)N_EDGES * 4);
    int* cntAct      = (int*)alloc((size_t)16 * 4);
    (void)ws_size; (void)in_sizes; (void)n_in; (void)out_size;  // ~96 MB used

    // ---- setup: single-block sort+CSR, then operand prep ----
    k_build<<<1, 1024, 0, stream>>>(nst, src, tgt, perm, inv, offs, eids, tgtp, cntAct);
    k_comp_eam<<<64, 256, 0, stream>>>(We, Wa, Wm, Wcomb);
    k_comp_fix<<<96, 256, 0, stream>>>(Wh, Wa, Wm, WfixC);
    k_pack_var<<<96, 256, 0, stream>>>(Wa, Wm, WvarSw);
    k_prep_ef<<<512, 256, 0, stream>>>(ef, eids, efp, maskp);
    k_prep_nf<<<64, 256, 0, stream>>>(nf, perm, nfp);
    k_h0<<<(N_NODES * HIDD) / 256, 256, 0, stream>>>(nf, Wh, inv, h, hbf);

    // eam[q][1024] = efp @ Wcomb (K=16 padded to 32), CSR-ordered rows
    k_gemm32<<<dim3(1024 / 64, N_EDGES / 256), 256, 0, stream>>>(efp, Wcomb, eam, 1024);
    // Tfix[N][1536] = nfp @ WfixC (K=32), permuted rows
    k_gemm32<<<dim3(TVAR / 64, N_NODES / 256), 256, 0, stream>>>(nfp, WfixC, Tfix, TVAR);

    // ---- iteration loop: in-place h, frozen-prefix skipping ----
    for (int i = 0; i < MAXS; ++i) {
        k_gemm128<<<dim3(TVAR / 64, N_NODES / 128), 256, 0, stream>>>(hbf, WvarSw, Tfix, Tcur,
                                                                      TVAR, cntAct, i);
        k_edge<<<N_NODES / 4, 256, 0, stream>>>(Tcur, eam, tgtp, offs, maskp, akn, cntAct,
                                                h, hbf, i);
    }
    k_out<<<(BATCH * ENCD) / 256, 256, 0, stream>>>(h, cs, inv, Wg, (float*)d_out);
}